// Round 7
// baseline (201.564 us; speedup 1.0000x reference)
//
#include <hip/hip_runtime.h>
#include <hip/hip_bf16.h>
#include <cstdint>

// Problem constants: B=2, T=2048, D_IN=D_OUT=1024, H=16, DH=64
#define SEQ_T 2048
#define DMODEL 1024
#define NHEAD 16
#define DHEAD 64

typedef __attribute__((ext_vector_type(8))) __bf16 bf16x8;
typedef __attribute__((ext_vector_type(4))) float floatx4;

static __device__ __forceinline__ uint16_t f2bf(float f) {
    union { float f; uint32_t u; } v; v.f = f;
    uint32_t r = v.u + 0x7FFFu + ((v.u >> 16) & 1u);   // RNE
    return (uint16_t)(r >> 16);
}

// ---------------- fp32 -> bf16 straight convert (x) ----------------
__global__ void mha_cvt_x(const float* __restrict__ x, uint16_t* __restrict__ xb) {
    int i = (blockIdx.x * blockDim.x + threadIdx.x) * 4;
    float4 f = *(const float4*)(x + i);
    union { uint16_t u[4]; uint64_t v; } o;
    o.u[0] = f2bf(f.x); o.u[1] = f2bf(f.y); o.u[2] = f2bf(f.z); o.u[3] = f2bf(f.w);
    *(uint64_t*)(xb + i) = o.v;
}

// ------------- fp32 -> bf16 convert + transpose (weights) -------------
__global__ void mha_cvt_wt(const float* __restrict__ W0, const float* __restrict__ W1,
                           const float* __restrict__ W2, const float* __restrict__ W3,
                           uint16_t* __restrict__ T0, uint16_t* __restrict__ T1,
                           uint16_t* __restrict__ T2, uint16_t* __restrict__ T3) {
    const float* W; uint16_t* Tt;
    switch (blockIdx.z) {
        case 0: W = W0; Tt = T0; break;
        case 1: W = W1; Tt = T1; break;
        case 2: W = W2; Tt = T2; break;
        default: W = W3; Tt = T3; break;
    }
    __shared__ float tile[64][65];
    const int c  = threadIdx.x & 63;
    const int r0 = threadIdx.x >> 6;
    const int R0 = blockIdx.y * 64, C0 = blockIdx.x * 64;
#pragma unroll
    for (int rr = 0; rr < 16; ++rr) {
        int r = r0 + rr * 4;
        tile[r][c] = W[(size_t)(R0 + r) * DMODEL + C0 + c];
    }
    __syncthreads();
#pragma unroll
    for (int rr = 0; rr < 16; ++rr) {
        int r = r0 + rr * 4;
        Tt[(size_t)(C0 + r) * DMODEL + R0 + c] = f2bf(tile[c][r]);
    }
}

// ------- m97-style bf16 MFMA GEMM (2-barrier, proven), B^T input -------
// MODE 0: bf16 row-major out.
// MODE 1: bf16 per-head transposed out Vt[(b*1024+col)*2048 + t], written
//         via an LDS transpose (two 64-col passes) with coalesced stores.
template<int MODE>
__device__ __forceinline__ void gemm128_body(
    const uint16_t* __restrict__ A, const uint16_t* __restrict__ Bt,
    uint16_t* __restrict__ outB) {
    const int K = DMODEL, N = DMODEL;
    __shared__ uint16_t As[128 * 32];   // 8 KB
    __shared__ uint16_t Bs[128 * 32];   // 8 KB
    const int tid  = threadIdx.x;
    const int wave = tid >> 6;
    const int lane = tid & 63;
    const int m0 = blockIdx.y * 128;
    const int n0 = blockIdx.x * 128;
    const int lr   = lane & 15;
    const int quad = lane >> 4;
    const int wm = wave >> 1, wn = wave & 1;

    floatx4 acc[4][4];
#pragma unroll
    for (int i = 0; i < 4; ++i)
#pragma unroll
        for (int j = 0; j < 4; ++j) acc[i][j] = (floatx4)0.0f;

    for (int k0 = 0; k0 < K; k0 += 32) {
#pragma unroll
        for (int i = 0; i < 2; ++i) {
            int chunk = i * 256 + wave * 64 + lane;
            int r  = chunk >> 2;
            int c8 = (chunk & 3) * 8;
            const uint16_t* ga = A  + (size_t)(m0 + r) * K + k0 + c8;
            const uint16_t* gb = Bt + (size_t)(n0 + r) * K + k0 + c8;
            uint16_t* la = &As[(size_t)(i * 256 + wave * 64) * 8];
            uint16_t* lb = &Bs[(size_t)(i * 256 + wave * 64) * 8];
            __builtin_amdgcn_global_load_lds((const __attribute__((address_space(1))) void*)ga,
                                             (__attribute__((address_space(3))) void*)la, 16, 0, 0);
            __builtin_amdgcn_global_load_lds((const __attribute__((address_space(1))) void*)gb,
                                             (__attribute__((address_space(3))) void*)lb, 16, 0, 0);
        }
        __syncthreads();
        bf16x8 af[4], bfr[4];
#pragma unroll
        for (int mi = 0; mi < 4; ++mi)
            af[mi] = *(const bf16x8*)&As[(wm * 64 + mi * 16 + lr) * 32 + quad * 8];
#pragma unroll
        for (int ni = 0; ni < 4; ++ni)
            bfr[ni] = *(const bf16x8*)&Bs[(wn * 64 + ni * 16 + lr) * 32 + quad * 8];
#pragma unroll
        for (int mi = 0; mi < 4; ++mi)
#pragma unroll
            for (int ni = 0; ni < 4; ++ni)
                acc[mi][ni] = __builtin_amdgcn_mfma_f32_16x16x32_bf16(af[mi], bfr[ni], acc[mi][ni], 0, 0, 0);
        __syncthreads();
    }
    if constexpr (MODE == 1) {
        // LDS-transpose epilogue: Ct[col_local][t_local], then coalesced rows
        __shared__ uint16_t Ct[64][136];   // pad 128->136 (16B mult) vs conflicts
        const int bb = m0 >> 11;           // batch index (tile never spans batch)
        const int t0 = m0 & 2047;
#pragma unroll
        for (int p = 0; p < 2; ++p) {
            if (wn == p) {
#pragma unroll
                for (int mi = 0; mi < 4; ++mi)
#pragma unroll
                    for (int ni = 0; ni < 4; ++ni) {
                        int cl = ni * 16 + lr;
                        int tl = wm * 64 + mi * 16 + quad * 4;
                        union { uint16_t u[4]; uint64_t v8; } pk;
#pragma unroll
                        for (int r = 0; r < 4; ++r) pk.u[r] = f2bf(acc[mi][ni][r]);
                        *(uint64_t*)&Ct[cl][tl] = pk.v8;
                    }
            }
            __syncthreads();
#pragma unroll
            for (int k = 0; k < 4; ++k) {
                int c  = k * 256 + tid;    // 1024 chunks of 16B
                int cl = c >> 4;
                int off = (c & 15) * 8;
                uint4 v = *(const uint4*)&Ct[cl][off];
                *(uint4*)&outB[((size_t)(bb * 1024 + n0 + p * 64 + cl)) * 2048 + t0 + off] = v;
            }
            __syncthreads();
        }
    } else {
#pragma unroll
        for (int mi = 0; mi < 4; ++mi)
#pragma unroll
            for (int ni = 0; ni < 4; ++ni) {
                int col = n0 + wn * 64 + ni * 16 + lr;
#pragma unroll
                for (int r = 0; r < 4; ++r) {
                    int row = m0 + wm * 64 + mi * 16 + quad * 4 + r;
                    outB[(size_t)row * N + col] = f2bf(acc[mi][ni][r]);
                }
            }
    }
}

__global__ __launch_bounds__(256) void mha_gemm_qkv(
    const uint16_t* __restrict__ A,
    const uint16_t* __restrict__ Wq, const uint16_t* __restrict__ Wk, const uint16_t* __restrict__ Wv,
    uint16_t* __restrict__ Q, uint16_t* __restrict__ K, uint16_t* __restrict__ Vt) {
    switch (blockIdx.z) {
        case 0:  gemm128_body<0>(A, Wq, Q);  break;
        case 1:  gemm128_body<0>(A, Wk, K);  break;
        default: gemm128_body<1>(A, Wv, Vt); break;
    }
}

// ---- out-projection GEMM: tile 128M x 64N, 4 waves (wave-tile 64x32) ----
// Grid 16x32 = 512 blocks = 2/CU -> 8 waves/CU (2x the old 128x128 grid's
// occupancy; that dispatch was 1 block/CU = 1 wave/SIMD, fully
// latency-exposed). 2-barrier staging. fp32 out + bias.
__global__ __launch_bounds__(256) void mha_gemm_out(
    const uint16_t* __restrict__ A, const uint16_t* __restrict__ Wot,
    float* __restrict__ out, const float* __restrict__ bias) {
    const int K = DMODEL, N = DMODEL;
    __shared__ uint16_t As[128 * 32];  // 8 KB
    __shared__ uint16_t Bs[64 * 32];   // 4 KB
    const int tid  = threadIdx.x;
    const int wave = tid >> 6;
    const int lane = tid & 63;
    const int m0 = blockIdx.y * 128;
    const int n0 = blockIdx.x * 64;
    const int lr   = lane & 15;
    const int quad = lane >> 4;
    const int wm = wave >> 1, wn = wave & 1;

    floatx4 acc[4][2];
#pragma unroll
    for (int i = 0; i < 4; ++i)
#pragma unroll
        for (int j = 0; j < 2; ++j) acc[i][j] = (floatx4)0.0f;

    for (int k0 = 0; k0 < K; k0 += 32) {
#pragma unroll
        for (int i = 0; i < 2; ++i) {   // A: 512 chunks
            int chunk = i * 256 + wave * 64 + lane;
            int r  = chunk >> 2;
            int c8 = (chunk & 3) * 8;
            const uint16_t* ga = A + (size_t)(m0 + r) * K + k0 + c8;
            uint16_t* la = &As[(size_t)(i * 256 + wave * 64) * 8];
            __builtin_amdgcn_global_load_lds((const __attribute__((address_space(1))) void*)ga,
                                             (__attribute__((address_space(3))) void*)la, 16, 0, 0);
        }
        {                               // B: 256 chunks
            int chunk = wave * 64 + lane;
            int r  = chunk >> 2;
            int c8 = (chunk & 3) * 8;
            const uint16_t* gb = Wot + (size_t)(n0 + r) * K + k0 + c8;
            uint16_t* lb = &Bs[(size_t)(wave * 64) * 8];
            __builtin_amdgcn_global_load_lds((const __attribute__((address_space(1))) void*)gb,
                                             (__attribute__((address_space(3))) void*)lb, 16, 0, 0);
        }
        __syncthreads();
        bf16x8 af[4], bfr[2];
#pragma unroll
        for (int mi = 0; mi < 4; ++mi)
            af[mi] = *(const bf16x8*)&As[(wm * 64 + mi * 16 + lr) * 32 + quad * 8];
#pragma unroll
        for (int ni = 0; ni < 2; ++ni)
            bfr[ni] = *(const bf16x8*)&Bs[(wn * 32 + ni * 16 + lr) * 32 + quad * 8];
#pragma unroll
        for (int mi = 0; mi < 4; ++mi)
#pragma unroll
            for (int ni = 0; ni < 2; ++ni)
                acc[mi][ni] = __builtin_amdgcn_mfma_f32_16x16x32_bf16(af[mi], bfr[ni], acc[mi][ni], 0, 0, 0);
        __syncthreads();
    }
#pragma unroll
    for (int mi = 0; mi < 4; ++mi)
#pragma unroll
        for (int ni = 0; ni < 2; ++ni) {
            int col = n0 + wn * 32 + ni * 16 + lr;
            float bv = bias[col];
#pragma unroll
            for (int r = 0; r < 4; ++r) {
                int row = m0 + wm * 64 + mi * 16 + quad * 4 + r;
                out[(size_t)row * N + col] = acc[mi][ni][r] + bv;
            }
        }
}

// ---------------- MFMA flash attention (causal, fixed-base softmax) -------
// 4 waves / 256 thr per block; one (b,h, 64-row q-tile-pair) per block.
// Balanced pairing: block p does q-tile 31-p (heavy) then p (light);
// TH+TL = 33 uniformly. Async single-barrier double-buffer staging.
// Fixed-base softmax p=exp(s/8), P truncated to bf16 with l consistent.
// Stage addressing hoisted out of the k-loop (loop-invariant swizzle).
__global__ __launch_bounds__(256) void mha_attn_mfma(
    const uint16_t* __restrict__ Q, const uint16_t* __restrict__ K,
    const uint16_t* __restrict__ Vt, uint16_t* __restrict__ ctx) {
    __shared__ alignas(16) uint16_t Ks[2][64 * 64];   // 16 KB
    __shared__ alignas(16) uint16_t Vs[2][64 * 64];   // 16 KB
    __shared__ alignas(16) uint16_t Pb[64 * 72];      // 9 KB

    const int tid  = threadIdx.x;
    const int wave = tid >> 6;
    const int lane = tid & 63;
    const int lr   = lane & 15;
    const int quad = lane >> 4;
    const int p  = blockIdx.x;             // 0..15
    const int h  = blockIdx.y;
    const int b  = blockIdx.z;
    const int jH = 31 - p, jL = p;         // 64-row q-tiles
    const int TH = jH + 1;
    const int TL = jL + 1;
    const int Ttot = TH + TL;              // 33 for every block

    // hoisted stage addressing (kv0-invariant parts)
    const uint16_t* kbase[2];
    const uint16_t* vbase[2];
#pragma unroll
    for (int i = 0; i < 2; ++i) {
        int c = i * 256 + tid;             // chunk 0..511 (16B each)
        int row = c >> 3, cs = c & 7;
        int csk = cs ^ (row & 7);          // XOR source swizzle; dest linear
        kbase[i] = K  + ((size_t)(b * SEQ_T) + row) * DMODEL + h * DHEAD + csk * 8;
        vbase[i] = Vt + ((size_t)(b * 1024 + h * DHEAD + row)) * 2048 + csk * 8;
    }

    int wrow = jH * 64 + wave * 16;        // this wave's q-row base
    bf16x8 qf0, qf1;
    {
        const size_t qb = ((size_t)(b * SEQ_T) + wrow + lr) * DMODEL + h * DHEAD;
        qf0 = *(const bf16x8*)(Q + qb + quad * 8);
        qf1 = *(const bf16x8*)(Q + qb + 32 + quad * 8);
    }
    floatx4 o[4];
#pragma unroll
    for (int nt = 0; nt < 4; ++nt) o[nt] = (floatx4)0.0f;
    float l[4] = {0.f, 0.f, 0.f, 0.f};

    auto stage = [&](int kv0, int buf) {
#pragma unroll
        for (int i = 0; i < 2; ++i) {
            const uint16_t* gk = kbase[i] + (size_t)kv0 * DMODEL;
            const uint16_t* gv = vbase[i] + kv0;
            uint16_t* lk = &Ks[buf][(i * 256 + wave * 64) * 8];
            uint16_t* lv = &Vs[buf][(i * 256 + wave * 64) * 8];
            __builtin_amdgcn_global_load_lds((const __attribute__((address_space(1))) void*)gk,
                                             (__attribute__((address_space(3))) void*)lk, 16, 0, 0);
            __builtin_amdgcn_global_load_lds((const __attribute__((address_space(1))) void*)gv,
                                             (__attribute__((address_space(3))) void*)lv, 16, 0, 0);
        }
    };
    auto epilogue = [&]() {
#pragma unroll
        for (int r = 0; r < 4; ++r) {
            float v = l[r];
            v += __shfl_xor(v, 1, 64);
            v += __shfl_xor(v, 2, 64);
            v += __shfl_xor(v, 4, 64);
            v += __shfl_xor(v, 8, 64);
            l[r] = 1.f / v;
        }
#pragma unroll
        for (int nt = 0; nt < 4; ++nt)
#pragma unroll
            for (int r = 0; r < 4; ++r) {
                size_t addr = ((size_t)(b * SEQ_T) + wrow + quad * 4 + r) * DMODEL + h * DHEAD + nt * 16 + lr;
                ctx[addr] = f2bf(o[nt][r] * l[r]);
            }
    };

    stage(0, 0);
    __syncthreads();                       // tile 0 ready
    int cur = 0;

    for (int t = 0; t < Ttot; ++t) {
        if (t + 1 < Ttot) {
            int nkv0 = ((t + 1 < TH) ? (t + 1) : (t + 1 - TH)) * 64;
            stage(nkv0, cur ^ 1);          // in flight behind compute
        }
        const int kv0 = ((t < TH) ? t : (t - TH)) * 64;

        // ---- S = Q K^T : C-layout col(lane&15)=key, row(quad*4+r)=q-row
        floatx4 s[4];
#pragma unroll
        for (int nt = 0; nt < 4; ++nt) {
            s[nt] = (floatx4)0.0f;
            int krow = nt * 16 + lr;
#pragma unroll
            for (int ks = 0; ks < 2; ++ks) {
                bf16x8 kf = *(const bf16x8*)&Ks[cur][krow * 64 + (((ks * 4 + quad) ^ (lr & 7)) * 8)];
                s[nt] = __builtin_amdgcn_mfma_f32_16x16x32_bf16(ks ? qf1 : qf0, kf, s[nt], 0, 0, 0);
            }
        }
        // ---- causal mask (diagonal tile only; wave-uniform branch)
        if (kv0 + 63 > wrow) {
#pragma unroll
            for (int nt = 0; nt < 4; ++nt) {
                int kcol = kv0 + nt * 16 + lr;
#pragma unroll
                for (int r = 0; r < 4; ++r) {
                    int qrow = wrow + quad * 4 + r;
                    if (kcol > qrow) s[nt][r] = -3e38f;
                }
            }
        }
        // ---- fixed-base softmax: p = exp(s/8); truncate to bf16, keep
        //      l consistent with the truncated numerator values
#pragma unroll
        for (int nt = 0; nt < 4; ++nt)
#pragma unroll
            for (int r = 0; r < 4; ++r) {
                float pe = __expf(s[nt][r] * 0.125f);
                uint32_t pu = __float_as_uint(pe);
                l[r] += __uint_as_float(pu & 0xffff0000u);
                Pb[(wave * 16 + quad * 4 + r) * 72 + nt * 16 + lr] = (uint16_t)(pu >> 16);
            }
        // ---- O += P V   (wave-private Pb region; same-wave LDS dep)
#pragma unroll
        for (int ks = 0; ks < 2; ++ks) {
            bf16x8 pfr = *(const bf16x8*)&Pb[(wave * 16 + lr) * 72 + ks * 32 + quad * 8];
#pragma unroll
            for (int nt = 0; nt < 4; ++nt) {
                int vrow = nt * 16 + lr;
                bf16x8 vf = *(const bf16x8*)&Vs[cur][vrow * 64 + (((ks * 4 + quad) ^ (lr & 7)) * 8)];
                o[nt] = __builtin_amdgcn_mfma_f32_16x16x32_bf16(pfr, vf, o[nt], 0, 0, 0);
            }
        }
        // ---- segment boundary: store heavy tile output, switch to light
        if (t == TH - 1) {
            epilogue();
            wrow = jL * 64 + wave * 16;
            const size_t qb = ((size_t)(b * SEQ_T) + wrow + lr) * DMODEL + h * DHEAD;
            qf0 = *(const bf16x8*)(Q + qb + quad * 8);
            qf1 = *(const bf16x8*)(Q + qb + 32 + quad * 8);
#pragma unroll
            for (int nt = 0; nt < 4; ++nt) o[nt] = (floatx4)0.0f;
#pragma unroll
            for (int r = 0; r < 4; ++r) l[r] = 0.f;
        }
        // single barrier: finishes all reads of buf[cur] AND (via implicit
        // vmcnt drain) completes the prefetch into buf[cur^1]
        __syncthreads();
        cur ^= 1;
    }
    epilogue();                            // light q-tile output
}

extern "C" void kernel_launch(void* const* d_in, const int* in_sizes, int n_in,
                              void* d_out, int out_size, void* d_ws, size_t ws_size,
                              hipStream_t stream) {
    const float* x  = (const float*)d_in[0];
    const float* Wq = (const float*)d_in[1];
    const float* Wk = (const float*)d_in[2];
    const float* Wv = (const float*)d_in[3];
    const float* Wo = (const float*)d_in[4];
    const float* bo = (const float*)d_in[5];
    float* out = (float*)d_out;

    char* ws = (char*)d_ws;
    const size_t SZ_X = (size_t)4096 * DMODEL * 2;   // 8 MB
    const size_t SZ_W = (size_t)DMODEL * DMODEL * 2; // 2 MB
    size_t off = 0;
    uint16_t* xb  = (uint16_t*)(ws + off); off += SZ_X;
    uint16_t* wqt = (uint16_t*)(ws + off); off += SZ_W;
    uint16_t* wkt = (uint16_t*)(ws + off); off += SZ_W;
    uint16_t* wvt = (uint16_t*)(ws + off); off += SZ_W;
    uint16_t* wot = (uint16_t*)(ws + off); off += SZ_W;
    uint16_t* Qb  = (uint16_t*)(ws + off); off += SZ_X;
    uint16_t* Kb  = (uint16_t*)(ws + off); off += SZ_X;
    uint16_t* Vtb = (uint16_t*)(ws + off); off += SZ_X;  // per-head transposed V
    uint16_t* Cb  = (uint16_t*)(ws + off); off += SZ_X;
    (void)ws_size; (void)in_sizes; (void)n_in; (void)out_size;

    mha_cvt_x<<<4096, 256, 0, stream>>>(x, xb);
    mha_cvt_wt<<<dim3(16, 16, 4), 256, 0, stream>>>(Wq, Wk, Wv, Wo, wqt, wkt, wvt, wot);
    mha_gemm_qkv<<<dim3(8, 32, 3), 256, 0, stream>>>(xb, wqt, wkt, wvt, Qb, Kb, Vtb);
    mha_attn_mfma<<<dim3(16, NHEAD, 2), 256, 0, stream>>>(Qb, Kb, Vtb, Cb);
    mha_gemm_out<<<dim3(16, 32), 256, 0, stream>>>(Cb, wot, out, bo);
}

// Round 8
// 198.596 us; speedup vs baseline: 1.0149x; 1.0149x over previous
//
#include <hip/hip_runtime.h>
#include <hip/hip_bf16.h>
#include <cstdint>

// Problem constants: B=2, T=2048, D_IN=D_OUT=1024, H=16, DH=64
#define SEQ_T 2048
#define DMODEL 1024
#define NHEAD 16
#define DHEAD 64

typedef __attribute__((ext_vector_type(8))) __bf16 bf16x8;
typedef __attribute__((ext_vector_type(4))) float floatx4;

static __device__ __forceinline__ uint16_t f2bf(float f) {
    union { float f; uint32_t u; } v; v.f = f;
    uint32_t r = v.u + 0x7FFFu + ((v.u >> 16) & 1u);   // RNE
    return (uint16_t)(r >> 16);
}

// ---------------- fp32 -> bf16 straight convert (x) ----------------
__global__ void mha_cvt_x(const float* __restrict__ x, uint16_t* __restrict__ xb) {
    int i = (blockIdx.x * blockDim.x + threadIdx.x) * 4;
    float4 f = *(const float4*)(x + i);
    union { uint16_t u[4]; uint64_t v; } o;
    o.u[0] = f2bf(f.x); o.u[1] = f2bf(f.y); o.u[2] = f2bf(f.z); o.u[3] = f2bf(f.w);
    *(uint64_t*)(xb + i) = o.v;
}

// ------------- fp32 -> bf16 convert + transpose (weights) -------------
__global__ void mha_cvt_wt(const float* __restrict__ W0, const float* __restrict__ W1,
                           const float* __restrict__ W2, const float* __restrict__ W3,
                           uint16_t* __restrict__ T0, uint16_t* __restrict__ T1,
                           uint16_t* __restrict__ T2, uint16_t* __restrict__ T3) {
    const float* W; uint16_t* Tt;
    switch (blockIdx.z) {
        case 0: W = W0; Tt = T0; break;
        case 1: W = W1; Tt = T1; break;
        case 2: W = W2; Tt = T2; break;
        default: W = W3; Tt = T3; break;
    }
    __shared__ float tile[64][65];
    const int c  = threadIdx.x & 63;
    const int r0 = threadIdx.x >> 6;
    const int R0 = blockIdx.y * 64, C0 = blockIdx.x * 64;
#pragma unroll
    for (int rr = 0; rr < 16; ++rr) {
        int r = r0 + rr * 4;
        tile[r][c] = W[(size_t)(R0 + r) * DMODEL + C0 + c];
    }
    __syncthreads();
#pragma unroll
    for (int rr = 0; rr < 16; ++rr) {
        int r = r0 + rr * 4;
        Tt[(size_t)(C0 + r) * DMODEL + R0 + c] = f2bf(tile[c][r]);
    }
}

// ------- bf16 MFMA GEMM, 64M x 128N tile, B^T input, swizzled LDS -------
// Chunk swizzle: linear LDS slot (r, q') holds source sub-chunk
// q' ^ ((r>>1)&3) -> fragment ds_read_b128 hits 8 distinct bank groups
// across 16 lanes (2-way only, free) instead of 8-way at stride-64B.
// MODE 0: bf16 row-major out. MODE 1: Vt[(b*1024+col)*2048+t] via
// smem-reusing LDS transpose with swizzled columns.
template<int MODE>
__device__ __forceinline__ void gemm64x128_body(
    const uint16_t* __restrict__ A, const uint16_t* __restrict__ Bt,
    uint16_t* __restrict__ outB) {
    const int K = DMODEL, N = DMODEL;
    __shared__ alignas(16) char smem[(MODE == 1) ? 18432 : 12288];
    uint16_t* As = (uint16_t*)smem;            // [64][32]
    uint16_t* Bs = (uint16_t*)(smem + 4096);   // [128][32]
    const int tid  = threadIdx.x;
    const int wave = tid >> 6;
    const int lane = tid & 63;
    const int m0 = blockIdx.y * 64;
    const int n0 = blockIdx.x * 128;
    const int lr   = lane & 15;
    const int quad = lane >> 4;

    floatx4 acc[4][2];
#pragma unroll
    for (int i = 0; i < 4; ++i)
#pragma unroll
        for (int j = 0; j < 2; ++j) acc[i][j] = (floatx4)0.0f;

    for (int k0 = 0; k0 < K; k0 += 32) {
        // 768 16B chunks: it=0 -> A (256), it=1,2 -> B (512)
#pragma unroll
        for (int it = 0; it < 3; ++it) {
            int c = it * 256 + wave * 64 + lane;
            if (it == 0) {
                int r = c >> 2, s = (c & 3) ^ ((r >> 1) & 3);
                const uint16_t* g = A + (size_t)(m0 + r) * K + k0 + s * 8;
                uint16_t* l = As + (size_t)c * 8;
                __builtin_amdgcn_global_load_lds((const __attribute__((address_space(1))) void*)g,
                                                 (__attribute__((address_space(3))) void*)l, 16, 0, 0);
            } else {
                int j = c - 256;
                int r = j >> 2, s = (j & 3) ^ ((r >> 1) & 3);
                const uint16_t* g = Bt + (size_t)(n0 + r) * K + k0 + s * 8;
                uint16_t* l = Bs + (size_t)j * 8;
                __builtin_amdgcn_global_load_lds((const __attribute__((address_space(1))) void*)g,
                                                 (__attribute__((address_space(3))) void*)l, 16, 0, 0);
            }
        }
        __syncthreads();
        bf16x8 af[4], bfr[2];
#pragma unroll
        for (int mi = 0; mi < 4; ++mi) {
            int row = mi * 16 + lr;
            af[mi] = *(const bf16x8*)&As[row * 32 + ((quad ^ ((row >> 1) & 3)) << 3)];
        }
#pragma unroll
        for (int ni = 0; ni < 2; ++ni) {
            int row = wave * 32 + ni * 16 + lr;
            bfr[ni] = *(const bf16x8*)&Bs[row * 32 + ((quad ^ ((row >> 1) & 3)) << 3)];
        }
#pragma unroll
        for (int mi = 0; mi < 4; ++mi)
#pragma unroll
            for (int ni = 0; ni < 2; ++ni)
                acc[mi][ni] = __builtin_amdgcn_mfma_f32_16x16x32_bf16(af[mi], bfr[ni], acc[mi][ni], 0, 0, 0);
        __syncthreads();
    }
    if constexpr (MODE == 1) {
        // transpose through smem (staging bufs dead after last barrier)
        uint16_t* Ct = (uint16_t*)smem;        // [128][72]
        const int bb = m0 >> 11, t0 = m0 & 2047;
#pragma unroll
        for (int mi = 0; mi < 4; ++mi)
#pragma unroll
            for (int ni = 0; ni < 2; ++ni) {
                int cl = wave * 32 + ni * 16 + lr;
                int tl = mi * 16 + quad * 4;
                int tls = tl ^ ((cl & 3) << 4);    // 2-way-only bank pattern
                union { uint16_t u[4]; uint64_t v8; } pk;
#pragma unroll
                for (int r = 0; r < 4; ++r) pk.u[r] = f2bf(acc[mi][ni][r]);
                *(uint64_t*)&Ct[cl * 72 + tls] = pk.v8;
            }
        __syncthreads();
#pragma unroll
        for (int k = 0; k < 4; ++k) {
            int c = k * 256 + tid;                 // 1024 chunks of 16B
            int cl = c >> 3, off = (c & 7) * 8;
            int offs = off ^ ((cl & 3) << 4);
            uint4 v = *(const uint4*)&Ct[cl * 72 + offs];
            *(uint4*)&outB[((size_t)(bb * 1024 + n0 + cl)) * 2048 + t0 + off] = v;
        }
    } else {
#pragma unroll
        for (int mi = 0; mi < 4; ++mi)
#pragma unroll
            for (int ni = 0; ni < 2; ++ni) {
                int col = n0 + wave * 32 + ni * 16 + lr;
#pragma unroll
                for (int r = 0; r < 4; ++r) {
                    int row = m0 + mi * 16 + quad * 4 + r;
                    outB[(size_t)row * N + col] = f2bf(acc[mi][ni][r]);
                }
            }
    }
}

__global__ __launch_bounds__(256) void mha_gemm_qkv(
    const uint16_t* __restrict__ A,
    const uint16_t* __restrict__ Wq, const uint16_t* __restrict__ Wk, const uint16_t* __restrict__ Wv,
    uint16_t* __restrict__ Q, uint16_t* __restrict__ K, uint16_t* __restrict__ Vt) {
    switch (blockIdx.z) {
        case 0:  gemm64x128_body<0>(A, Wq, Q);  break;
        case 1:  gemm64x128_body<0>(A, Wk, K);  break;
        default: gemm64x128_body<1>(A, Wv, Vt); break;
    }
}

// ---- out-projection GEMM: 64M x 64N tile, grid (16,64)=1024 = 4/CU ----
__global__ __launch_bounds__(256) void mha_gemm_out(
    const uint16_t* __restrict__ A, const uint16_t* __restrict__ Wot,
    float* __restrict__ out, const float* __restrict__ bias) {
    const int K = DMODEL, N = DMODEL;
    __shared__ alignas(16) uint16_t As[64 * 32];   // 4 KB
    __shared__ alignas(16) uint16_t Bs[64 * 32];   // 4 KB
    const int tid  = threadIdx.x;
    const int wave = tid >> 6;
    const int lane = tid & 63;
    const int m0 = blockIdx.y * 64;
    const int n0 = blockIdx.x * 64;
    const int lr   = lane & 15;
    const int quad = lane >> 4;

    floatx4 acc[4];
#pragma unroll
    for (int i = 0; i < 4; ++i) acc[i] = (floatx4)0.0f;

    for (int k0 = 0; k0 < K; k0 += 32) {
#pragma unroll
        for (int it = 0; it < 2; ++it) {
            int c = it * 256 + wave * 64 + lane;   // A: 0..255, B: 256..511
            int j = c & 255;
            int r = j >> 2, s = (j & 3) ^ ((r >> 1) & 3);
            const uint16_t* g = (it == 0) ? (A   + (size_t)(m0 + r) * K + k0 + s * 8)
                                          : (Wot + (size_t)(n0 + r) * K + k0 + s * 8);
            uint16_t* l = ((it == 0) ? As : Bs) + (size_t)j * 8;
            __builtin_amdgcn_global_load_lds((const __attribute__((address_space(1))) void*)g,
                                             (__attribute__((address_space(3))) void*)l, 16, 0, 0);
        }
        __syncthreads();
        bf16x8 af[4], bfr;
#pragma unroll
        for (int mi = 0; mi < 4; ++mi) {
            int row = mi * 16 + lr;
            af[mi] = *(const bf16x8*)&As[row * 32 + ((quad ^ ((row >> 1) & 3)) << 3)];
        }
        {
            int row = wave * 16 + lr;
            bfr = *(const bf16x8*)&Bs[row * 32 + ((quad ^ ((row >> 1) & 3)) << 3)];
        }
#pragma unroll
        for (int mi = 0; mi < 4; ++mi)
            acc[mi] = __builtin_amdgcn_mfma_f32_16x16x32_bf16(af[mi], bfr, acc[mi], 0, 0, 0);
        __syncthreads();
    }
    int col = n0 + wave * 16 + lr;
    float bv = bias[col];
#pragma unroll
    for (int mi = 0; mi < 4; ++mi)
#pragma unroll
        for (int r = 0; r < 4; ++r) {
            int row = m0 + mi * 16 + quad * 4 + r;
            out[(size_t)row * N + col] = acc[mi][r] + bv;
        }
}

// ---------------- MFMA flash attention (causal, fixed-base softmax) -------
// Grid (h, p, b): XCD = linear%8 = h%8 -> all 16 q-blocks of one head land
// on one XCD, keeping its K/V hot in that XCD's L2 (no 8x duplication).
// 4 waves / 256 thr; balanced pairing jH=31-p then jL=p (33 iters always).
// Async single-barrier double-buffer staging; fixed-base softmax p=exp(s/8).
__global__ __launch_bounds__(256) void mha_attn_mfma(
    const uint16_t* __restrict__ Q, const uint16_t* __restrict__ K,
    const uint16_t* __restrict__ Vt, uint16_t* __restrict__ ctx) {
    __shared__ alignas(16) uint16_t Ks[2][64 * 64];   // 16 KB
    __shared__ alignas(16) uint16_t Vs[2][64 * 64];   // 16 KB
    __shared__ alignas(16) uint16_t Pb[64 * 72];      // 9 KB

    const int tid  = threadIdx.x;
    const int wave = tid >> 6;
    const int lane = tid & 63;
    const int lr   = lane & 15;
    const int quad = lane >> 4;
    const int h  = blockIdx.x;             // head fastest -> XCD locality
    const int p  = blockIdx.y;             // 0..15
    const int b  = blockIdx.z;
    const int jH = 31 - p, jL = p;         // 64-row q-tiles
    const int TH = jH + 1;
    const int TL = jL + 1;
    const int Ttot = TH + TL;              // 33 for every block

    // hoisted stage addressing (kv0-invariant parts)
    const uint16_t* kbase[2];
    const uint16_t* vbase[2];
#pragma unroll
    for (int i = 0; i < 2; ++i) {
        int c = i * 256 + tid;             // chunk 0..511 (16B each)
        int row = c >> 3, cs = c & 7;
        int csk = cs ^ (row & 7);          // XOR source swizzle; dest linear
        kbase[i] = K  + ((size_t)(b * SEQ_T) + row) * DMODEL + h * DHEAD + csk * 8;
        vbase[i] = Vt + ((size_t)(b * 1024 + h * DHEAD + row)) * 2048 + csk * 8;
    }

    int wrow = jH * 64 + wave * 16;        // this wave's q-row base
    bf16x8 qf0, qf1;
    {
        const size_t qb = ((size_t)(b * SEQ_T) + wrow + lr) * DMODEL + h * DHEAD;
        qf0 = *(const bf16x8*)(Q + qb + quad * 8);
        qf1 = *(const bf16x8*)(Q + qb + 32 + quad * 8);
    }
    floatx4 o[4];
#pragma unroll
    for (int nt = 0; nt < 4; ++nt) o[nt] = (floatx4)0.0f;
    float l[4] = {0.f, 0.f, 0.f, 0.f};

    auto stage = [&](int kv0, int buf) {
#pragma unroll
        for (int i = 0; i < 2; ++i) {
            const uint16_t* gk = kbase[i] + (size_t)kv0 * DMODEL;
            const uint16_t* gv = vbase[i] + kv0;
            uint16_t* lk = &Ks[buf][(i * 256 + wave * 64) * 8];
            uint16_t* lv = &Vs[buf][(i * 256 + wave * 64) * 8];
            __builtin_amdgcn_global_load_lds((const __attribute__((address_space(1))) void*)gk,
                                             (__attribute__((address_space(3))) void*)lk, 16, 0, 0);
            __builtin_amdgcn_global_load_lds((const __attribute__((address_space(1))) void*)gv,
                                             (__attribute__((address_space(3))) void*)lv, 16, 0, 0);
        }
    };
    auto epilogue = [&]() {
#pragma unroll
        for (int r = 0; r < 4; ++r) {
            float v = l[r];
            v += __shfl_xor(v, 1, 64);
            v += __shfl_xor(v, 2, 64);
            v += __shfl_xor(v, 4, 64);
            v += __shfl_xor(v, 8, 64);
            l[r] = 1.f / v;
        }
#pragma unroll
        for (int nt = 0; nt < 4; ++nt)
#pragma unroll
            for (int r = 0; r < 4; ++r) {
                size_t addr = ((size_t)(b * SEQ_T) + wrow + quad * 4 + r) * DMODEL + h * DHEAD + nt * 16 + lr;
                ctx[addr] = f2bf(o[nt][r] * l[r]);
            }
    };

    stage(0, 0);
    __syncthreads();                       // tile 0 ready
    int cur = 0;

    for (int t = 0; t < Ttot; ++t) {
        if (t + 1 < Ttot) {
            int nkv0 = ((t + 1 < TH) ? (t + 1) : (t + 1 - TH)) * 64;
            stage(nkv0, cur ^ 1);          // in flight behind compute
        }
        const int kv0 = ((t < TH) ? t : (t - TH)) * 64;

        // ---- S = Q K^T : C-layout col(lane&15)=key, row(quad*4+r)=q-row
        floatx4 s[4];
#pragma unroll
        for (int nt = 0; nt < 4; ++nt) {
            s[nt] = (floatx4)0.0f;
            int krow = nt * 16 + lr;
#pragma unroll
            for (int ks = 0; ks < 2; ++ks) {
                bf16x8 kf = *(const bf16x8*)&Ks[cur][krow * 64 + (((ks * 4 + quad) ^ (lr & 7)) * 8)];
                s[nt] = __builtin_amdgcn_mfma_f32_16x16x32_bf16(ks ? qf1 : qf0, kf, s[nt], 0, 0, 0);
            }
        }
        // ---- causal mask (diagonal tile only; wave-uniform branch)
        if (kv0 + 63 > wrow) {
#pragma unroll
            for (int nt = 0; nt < 4; ++nt) {
                int kcol = kv0 + nt * 16 + lr;
#pragma unroll
                for (int r = 0; r < 4; ++r) {
                    int qrow = wrow + quad * 4 + r;
                    if (kcol > qrow) s[nt][r] = -3e38f;
                }
            }
        }
        // ---- fixed-base softmax: p = exp(s/8); truncate to bf16, keep
        //      l consistent with the truncated numerator values
#pragma unroll
        for (int nt = 0; nt < 4; ++nt)
#pragma unroll
            for (int r = 0; r < 4; ++r) {
                float pe = __expf(s[nt][r] * 0.125f);
                uint32_t pu = __float_as_uint(pe);
                l[r] += __uint_as_float(pu & 0xffff0000u);
                Pb[(wave * 16 + quad * 4 + r) * 72 + nt * 16 + lr] = (uint16_t)(pu >> 16);
            }
        // ---- O += P V   (wave-private Pb region; same-wave LDS dep)
#pragma unroll
        for (int ks = 0; ks < 2; ++ks) {
            bf16x8 pfr = *(const bf16x8*)&Pb[(wave * 16 + lr) * 72 + ks * 32 + quad * 8];
#pragma unroll
            for (int nt = 0; nt < 4; ++nt) {
                int vrow = nt * 16 + lr;
                bf16x8 vf = *(const bf16x8*)&Vs[cur][vrow * 64 + (((ks * 4 + quad) ^ (lr & 7)) * 8)];
                o[nt] = __builtin_amdgcn_mfma_f32_16x16x32_bf16(pfr, vf, o[nt], 0, 0, 0);
            }
        }
        // ---- segment boundary: store heavy tile output, switch to light
        if (t == TH - 1) {
            epilogue();
            wrow = jL * 64 + wave * 16;
            const size_t qb = ((size_t)(b * SEQ_T) + wrow + lr) * DMODEL + h * DHEAD;
            qf0 = *(const bf16x8*)(Q + qb + quad * 8);
            qf1 = *(const bf16x8*)(Q + qb + 32 + quad * 8);
#pragma unroll
            for (int nt = 0; nt < 4; ++nt) o[nt] = (floatx4)0.0f;
#pragma unroll
            for (int r = 0; r < 4; ++r) l[r] = 0.f;
        }
        // single barrier: finishes all reads of buf[cur] AND (via implicit
        // vmcnt drain) completes the prefetch into buf[cur^1]
        __syncthreads();
        cur ^= 1;
    }
    epilogue();                            // light q-tile output
}

extern "C" void kernel_launch(void* const* d_in, const int* in_sizes, int n_in,
                              void* d_out, int out_size, void* d_ws, size_t ws_size,
                              hipStream_t stream) {
    const float* x  = (const float*)d_in[0];
    const float* Wq = (const float*)d_in[1];
    const float* Wk = (const float*)d_in[2];
    const float* Wv = (const float*)d_in[3];
    const float* Wo = (const float*)d_in[4];
    const float* bo = (const float*)d_in[5];
    float* out = (float*)d_out;

    char* ws = (char*)d_ws;
    const size_t SZ_X = (size_t)4096 * DMODEL * 2;   // 8 MB
    const size_t SZ_W = (size_t)DMODEL * DMODEL * 2; // 2 MB
    size_t off = 0;
    uint16_t* xb  = (uint16_t*)(ws + off); off += SZ_X;
    uint16_t* wqt = (uint16_t*)(ws + off); off += SZ_W;
    uint16_t* wkt = (uint16_t*)(ws + off); off += SZ_W;
    uint16_t* wvt = (uint16_t*)(ws + off); off += SZ_W;
    uint16_t* wot = (uint16_t*)(ws + off); off += SZ_W;
    uint16_t* Qb  = (uint16_t*)(ws + off); off += SZ_X;
    uint16_t* Kb  = (uint16_t*)(ws + off); off += SZ_X;
    uint16_t* Vtb = (uint16_t*)(ws + off); off += SZ_X;  // per-head transposed V
    uint16_t* Cb  = (uint16_t*)(ws + off); off += SZ_X;
    (void)ws_size; (void)in_sizes; (void)n_in; (void)out_size;

    mha_cvt_x<<<4096, 256, 0, stream>>>(x, xb);
    mha_cvt_wt<<<dim3(16, 16, 4), 256, 0, stream>>>(Wq, Wk, Wv, Wo, wqt, wkt, wvt, wot);
    mha_gemm_qkv<<<dim3(8, 64, 3), 256, 0, stream>>>(xb, wqt, wkt, wvt, Qb, Kb, Vtb);
    mha_attn_mfma<<<dim3(NHEAD, 16, 2), 256, 0, stream>>>(Qb, Kb, Vtb, Cb);
    mha_gemm_out<<<dim3(16, 64), 256, 0, stream>>>(Cb, wot, out, bo);
}